// Round 10
// baseline (1970.825 us; speedup 1.0000x reference)
//
#include <hip/hip_runtime.h>

// Problem constants (shapes fixed by the reference)
#define HP    1017
#define WP    1017
#define NPIX  (HP*WP)          // 1034289
#define N3    (NPIX/3)         // 344763
#define W_IMG 1024
#define RATE  0.001f
#define EPSV  1e-7f

// temporal blocking geometry
#define K_ITERS 4
#define RY   32                // output rows per band
#define CW   64                // output cols per col-tile
#define HALO 8                 // 2*K_ITERS
#define IY   (RY + 2*HALO)     // 48
#define IC   (CW + 2*HALO)     // 80
#define ICP  82                // padded LDS stride (bank spread for fixed-row mapping)
#define NBX  16                // col tiles (16*64 = 1024 >= 1017)
#define NBY  32                // row bands (32*32 = 1024 >= 1017)
#define TBT  384               // 48 rows x 8 col-threads

typedef _Float16 half_t;

__device__ __forceinline__ float fast_rcp(float x) { return __builtin_amdgcn_rcpf(x); }

// ---------------------------------------------------------------------------
// init: t0 = tlb = max_c(1 - center/A), and pack img_c (fp16) contiguously
// ---------------------------------------------------------------------------
__global__ void init_kernel(const float* __restrict__ img, const float* __restrict__ A,
                            half_t* __restrict__ img_c, float* __restrict__ t0) {
    int b = blockIdx.x * blockDim.x + threadIdx.x;
    int a = blockIdx.y;
    if (b >= WP) return;
    int m = a * WP + b;
    float A0 = A[0], A1 = A[1], A2 = A[2];
    const float* src = img + ((size_t)a * W_IMG + b) * 3;
    img_c[3*m+0] = (half_t)src[0];
    img_c[3*m+1] = (half_t)src[1];
    img_c[3*m+2] = (half_t)src[2];
    const float* cen = img + ((size_t)(a+3) * W_IMG + (b+3)) * 3;
    float t = 1.0f - cen[0] / A0;
    t = fmaxf(t, 1.0f - cen[1] / A1);
    t = fmaxf(t, 1.0f - cen[2] / A2);
    t0[m] = t;
}

// ---------------------------------------------------------------------------
// temporal-blocked kernel: K_ITERS GD iterations in LDS.
// Fixed-row mapping: thread tid owns tile row i = tid>>3, cols j = (tid&7)+8k.
// Buffers: t (f32, in-place), lg (f32), sig (f16), r (f16); r/lg written
// whenever t is written (load pass and t-update pass) => 5 trans/cell-level.
// Tile cell (i,j) hosts flat pixel m = (rbase+i)*WP + (cbase+j); cols may run
// past [0,WP) — flat wrap semantics are automatic; (a,b) via compare, no div.
// ---------------------------------------------------------------------------
__global__ __launch_bounds__(TBT) void tb_kernel(
    const float* __restrict__ tin, float* __restrict__ tout,
    const half_t* __restrict__ img_c, const float* __restrict__ A)
{
    __shared__ float  tls[IY][ICP];
    __shared__ float  lgl[IY][ICP];
    __shared__ half_t sgl[IY][ICP];
    __shared__ half_t rll[IY][ICP];

    const int tid  = threadIdx.x;
    const int i    = tid >> 3;            // tile row, fixed per thread
    const int jt   = tid & 7;
    const int rbase = blockIdx.y * RY - HALO;
    const int cbase = blockIdx.x * CW - HALO;
    const int arow  = rbase + i;
    const int m_base = arow * WP + cbase; // hoisted: flat index of (i, j=0)
    const float A0 = A[0], A1 = A[1], A2 = A[2];

    // ---- load t_k + fused r/lg ----
    #pragma unroll
    for (int k = 0; k < 10; ++k) {
        int j = jt + 8*k;                 // 0..79
        int m = m_base + j;
        float v = 1.0f;
        if (m >= 0 && m < NPIX) v = tin[m];
        tls[i][j] = v;
        rll[i][j] = (half_t)fast_rcp(v);
        lgl[i][j] = __logf(v <= 0.0f ? EPSV : v);
    }
    __syncthreads();

    #pragma unroll 1
    for (int lvl = 0; lvl < K_ITERS; ++lvl) {
        // --- pass B: sig at margin ms (reads r, img_c) ---
        const int ms = 2*lvl + 1;
        if (i >= ms && i < IY - ms) {
            for (int k = 0; k < 10; ++k) {
                int j = jt + 8*k;
                if (j < ms || j >= IC - ms) continue;
                int m = m_base + j;
                if (m < 0 || m >= NPIX) continue;
                float r0 = (float)rll[i][j];
                float rm = (m > 0)        ? (float)rll[i][j-1] : r0;
                float rp = (m < NPIX - 1) ? (float)rll[i][j+1] : r0;
                int base = 3 * m;
                float fm1 = (float)img_c[m > 0        ? base - 1 : 0];
                float f0  = (float)img_c[base + 0];
                float f1  = (float)img_c[base + 1];
                float f2  = (float)img_c[base + 2];
                float f3  = (float)img_c[m < NPIX - 1 ? base + 3 : base + 2];
                float dm1 = (fm1 - A2) * rm + A2;
                float d0  = (f0  - A0) * r0 + A0;
                float d1  = (f1  - A1) * r0 + A1;
                float d2  = (f2  - A2) * r0 + A2;
                float d3  = (f3  - A0) * rp + A0;
                float y0 = 0.5f * (d1 - dm1);
                float y1 = 0.5f * (d2 - d0);
                float y2 = 0.5f * (d3 - d1);
                if (m == 0      ) y0 = d1 - d0;
                if (m == N3     ) y0 = d1 - d0;
                if (m == 2*N3   ) y0 = d1 - d0;
                if (m == N3 - 1 ) y2 = d2 - d1;
                if (m == 2*N3-1 ) y2 = d2 - d1;
                if (m == NPIX-1 ) y2 = d2 - d1;
                float l2 = sqrtf(y0*y0 + y1*y1 + y2*y2);
                sgl[i][j] = (half_t)fast_rcp(1.0f + __expf(48.0f * (l2 - 0.1f)));
            }
        }
        __syncthreads();
        // --- pass C: t update (in place) at margin mt, fused r/lg of t_new ---
        const int mt = 2*lvl + 2;
        if (i >= mt && i < IY - mt) {
            for (int k = 0; k < 10; ++k) {
                int j = jt + 8*k;
                if (j < mt || j >= IC - mt) continue;
                int m = m_base + j;
                if (m < 0 || m >= NPIX) continue;
                int col = cbase + j;
                int a = arow, b = col;
                if (col < 0)         { a = arow - 1; b = col + WP; }
                else if (col >= WP)  { a = arow + 1; b = col - WP; }
                float tc = tls[i][j];
                bool  neg = (tc <= 0.0f);
                float w0 = neg ? EPSV : tc;
                float rw = neg ? 1e7f : (float)rll[i][j];
                float lgC = lgl[i][j];
                float acc = 0.0f;
                if (b >= 1)
                    acc += (lgC - ((b >= 2)    ? lgl[i][j-2] : 0.0f)) * (float)sgl[i][j-1];
                if (b <= WP-2)
                    acc -= ((((b <= WP-3)) ? lgl[i][j+2] : 0.0f) - lgC) * (float)sgl[i][j+1];
                if (a <= HP-2)
                    acc += (lgC - ((a <= HP-3) ? lgl[i+2][j] : 0.0f)) * (float)sgl[i+1][j];
                if (a >= 1)
                    acc -= (((a >= 2)    ? lgl[i-2][j] : 0.0f) - lgC) * (float)sgl[i-1][j];
                float v = w0 - RATE * 2.0f * acc * rw;
                tls[i][j] = v;
                rll[i][j] = (half_t)fast_rcp(v);
                lgl[i][j] = __logf(v <= 0.0f ? EPSV : v);
            }
        }
        __syncthreads();
    }

    // ---- store t_{k+4} for the owned output region ----
    if (i >= HALO && i < IY - HALO) {
        for (int k = 0; k < 10; ++k) {
            int j = jt + 8*k;
            if (j < HALO || j >= IC - HALO) continue;
            int m = m_base + j;
            if (m >= 0 && m < NPIX) tout[m] = tls[i][j];
        }
    }
}

// ---------------------------------------------------------------------------
// final dehaze from t_100
// ---------------------------------------------------------------------------
__global__ void out_kernel(const float* __restrict__ t, const half_t* __restrict__ img_c,
                           const float* __restrict__ A, float* __restrict__ out) {
    int m = blockIdx.x * blockDim.x + threadIdx.x;
    if (m >= NPIX) return;
    float tv = t[m];
    float A0 = A[0], A1 = A[1], A2 = A[2];
    float r = 1.0f / tv;               // precise div for the final output
    out[3*m+0] = ((float)img_c[3*m+0] - A0) * r + A0;
    out[3*m+1] = ((float)img_c[3*m+1] - A1) * r + A1;
    out[3*m+2] = ((float)img_c[3*m+2] - A2) * r + A2;
}

extern "C" void kernel_launch(void* const* d_in, const int* in_sizes, int n_in,
                              void* d_out, int out_size, void* d_ws, size_t ws_size,
                              hipStream_t stream) {
    const float* img = (const float*)d_in[0];
    const float* A   = (const float*)d_in[1];
    // workspace: t_a[N] f32 | t_b[N] f32 | img_c[3N] f16
    float*  ws    = (float*)d_ws;
    float*  t_a   = ws;
    float*  t_b   = t_a + NPIX;
    half_t* img_c = (half_t*)(t_b + NPIX);

    dim3 blk2(256, 1, 1);
    dim3 grd2((WP + 255) / 256, HP, 1);
    int blk1 = 256;
    int grd1 = (NPIX + blk1 - 1) / blk1;

    hipLaunchKernelGGL(init_kernel, grd2, blk2, 0, stream, img, A, img_c, t_a);

    float* tsrc = t_a;
    float* tdst = t_b;
    for (int d = 0; d < 25; ++d) {               // 25 dispatches x 4 iters = 100
        hipLaunchKernelGGL(tb_kernel, dim3(NBX, NBY), dim3(TBT), 0, stream,
                           tsrc, tdst, img_c, A);
        float* tmp = tsrc; tsrc = tdst; tdst = tmp;
    }
    hipLaunchKernelGGL(out_kernel, dim3(grd1), dim3(blk1), 0, stream,
                       tsrc, img_c, A, (float*)d_out);
}

// Round 11
// 1076.845 us; speedup vs baseline: 1.8302x; 1.8302x over previous
//
#include <hip/hip_runtime.h>

// Problem constants (shapes fixed by the reference)
#define HP    1017
#define WP    1017
#define NPIX  (HP*WP)          // 1034289
#define N3    (NPIX/3)         // 344763
#define W_IMG 1024
#define RATE  0.001f
#define EPSV  1e-7f

// temporal blocking geometry
#define K_ITERS 4
#define RY   16                // output rows per band
#define CW   128               // output cols per col-tile
#define HALO 8                 // 2*K_ITERS
#define IY   (RY + 2*HALO)     // 32
#define IC   (CW + 2*HALO)     // 144
#define ICP  IC                // contiguous mapping => stride-1 accesses, no pad needed
#define NBX  8                 // 8*128 = 1024 >= 1017
#define NBY  64                // 64*16 = 1024 >= 1017
#define TBT  512               // threads; 32*144 = 4608 = 512*9 cells exactly
#define NSLOT 9

typedef _Float16 half_t;

__device__ __forceinline__ float fast_rcp(float x) { return __builtin_amdgcn_rcpf(x); }

// ---------------------------------------------------------------------------
// init: t0 = tlb = max_c(1 - center/A), and pack img_c (fp16) contiguously
// ---------------------------------------------------------------------------
__global__ void init_kernel(const float* __restrict__ img, const float* __restrict__ A,
                            half_t* __restrict__ img_c, float* __restrict__ t0) {
    int b = blockIdx.x * blockDim.x + threadIdx.x;
    int a = blockIdx.y;
    if (b >= WP) return;
    int m = a * WP + b;
    float A0 = A[0], A1 = A[1], A2 = A[2];
    const float* src = img + ((size_t)a * W_IMG + b) * 3;
    img_c[3*m+0] = (half_t)src[0];
    img_c[3*m+1] = (half_t)src[1];
    img_c[3*m+2] = (half_t)src[2];
    const float* cen = img + ((size_t)(a+3) * W_IMG + (b+3)) * 3;
    float t = 1.0f - cen[0] / A0;
    t = fmaxf(t, 1.0f - cen[1] / A1);
    t = fmaxf(t, 1.0f - cen[2] / A2);
    t0[m] = t;
}

// ---------------------------------------------------------------------------
// slot walk: contiguous cells tid + 512*s over the 32x144 tile, division-free.
// Maintains (i, j, m, arow, col) incrementally:  +512 = +3 rows +80 cols.
// ---------------------------------------------------------------------------
template <typename F>
__device__ __forceinline__ void for_slots(int tid, int rbase, int cbase, F f) {
    int i = tid / IC;                 // one division per kernel (tid < 512)
    int j = tid - i * IC;
    int arow = rbase + i;
    int col  = cbase + j;
    int m    = arow * WP + col;
    #pragma unroll 1
    for (int s = 0; s < NSLOT; ++s) {
        f(i, j, m, arow, col);
        j += 80; col += 80; m += 3*WP + 80; i += 3; arow += 3;
        if (j >= IC) { j -= IC; col -= IC; m += WP - IC; i += 1; arow += 1; }
    }
}

// ---------------------------------------------------------------------------
// temporal-blocked kernel: 4 GD iterations in LDS.
// Buffers: lg f32 ping-pong, sig f32 (per-level scratch), r f16 (in-place,
// race-free: pass C reads r only at its own cell). No t buffer: w0 = exp(lg).
// Tile cell (i,j) hosts flat pixel m=(rbase+i)*WP+(cbase+j); out-of-range cols
// wrap in flat order automatically; (a,b) recovered via compares, no division.
// ---------------------------------------------------------------------------
__global__ __launch_bounds__(TBT, 4) void tb_kernel(
    const float* __restrict__ tin, float* __restrict__ tout,
    const half_t* __restrict__ img_c, const float* __restrict__ A)
{
    __shared__ float  lgl[2][IY][ICP];
    __shared__ float  sgl[IY][ICP];
    __shared__ half_t rll[IY][ICP];

    const int tid   = threadIdx.x;
    const int rbase = blockIdx.y * RY - HALO;
    const int cbase = blockIdx.x * CW - HALO;
    const float A0 = A[0], A1 = A[1], A2 = A[2];

    // ---- load: r = rcp(t_k), lg = log(guard(t_k));  OOB cells -> t=1 (lg=0, r=1)
    for_slots(tid, rbase, cbase, [&](int i, int j, int m, int arow, int col) {
        float v = 1.0f;
        if ((unsigned)m < (unsigned)NPIX) v = tin[m];
        rll[i][j] = (half_t)fast_rcp(v);
        lgl[0][i][j] = __logf(v <= 0.0f ? EPSV : v);
    });
    __syncthreads();

    #pragma unroll
    for (int lvl = 0; lvl < K_ITERS; ++lvl) {
        float (* __restrict__ lgc)[ICP] = lgl[lvl & 1];
        float (* __restrict__ lgn)[ICP] = lgl[(lvl & 1) ^ 1];
        const int ms = 2*lvl + 1;
        // --- pass B: sig from r (flat +/-1) + img_c ---
        for_slots(tid, rbase, cbase, [&](int i, int j, int m, int arow, int col) {
            float s = 0.0f;
            if (i >= ms && i < IY-ms && j >= ms && j < IC-ms && (unsigned)m < (unsigned)NPIX) {
                float r0 = (float)rll[i][j];
                float rm = (m > 0)        ? (float)rll[i][j-1] : r0;
                float rp = (m < NPIX - 1) ? (float)rll[i][j+1] : r0;
                int base = 3 * m;
                float fm1 = (float)img_c[m > 0        ? base - 1 : 0];
                float f0  = (float)img_c[base + 0];
                float f1  = (float)img_c[base + 1];
                float f2  = (float)img_c[base + 2];
                float f3  = (float)img_c[m < NPIX - 1 ? base + 3 : base + 2];
                float dm1 = (fm1 - A2) * rm + A2;
                float d0  = (f0  - A0) * r0 + A0;
                float d1  = (f1  - A1) * r0 + A1;
                float d2  = (f2  - A2) * r0 + A2;
                float d3  = (f3  - A0) * rp + A0;
                float y0 = 0.5f * (d1 - dm1);
                float y1 = 0.5f * (d2 - d0);
                float y2 = 0.5f * (d3 - d1);
                if (m == 0      ) y0 = d1 - d0;
                if (m == N3     ) y0 = d1 - d0;
                if (m == 2*N3   ) y0 = d1 - d0;
                if (m == N3 - 1 ) y2 = d2 - d1;
                if (m == 2*N3-1 ) y2 = d2 - d1;
                if (m == NPIX-1 ) y2 = d2 - d1;
                float l2 = sqrtf(y0*y0 + y1*y1 + y2*y2);
                s = fast_rcp(1.0f + __expf(48.0f * (l2 - 0.1f)));
            }
            sgl[i][j] = s;
        });
        __syncthreads();
        // --- pass C: t update; w0 = exp(lgC); writes lg_new + r_new (or tout at last lvl)
        const int mt = 2*lvl + 2;
        for_slots(tid, rbase, cbase, [&](int i, int j, int m, int arow, int col) {
            if (i >= mt && i < IY-mt && j >= mt && j < IC-mt && (unsigned)m < (unsigned)NPIX) {
                int a = arow, b = col;
                if (col < 0)        { a = arow - 1; b = col + WP; }
                else if (col >= WP) { a = arow + 1; b = col - WP; }
                float lgC = lgc[i][j];
                float acc = 0.0f;
                if (b >= 1)
                    acc += (lgC - ((b >= 2)    ? lgc[i][j-2] : 0.0f)) * sgl[i][j-1];
                if (b <= WP-2)
                    acc -= ((((b <= WP-3)) ? lgc[i][j+2] : 0.0f) - lgC) * sgl[i][j+1];
                if (a <= HP-2)
                    acc += (lgC - ((a <= HP-3) ? lgc[i+2][j] : 0.0f)) * sgl[i+1][j];
                if (a >= 1)
                    acc -= (((a >= 2)    ? lgc[i-2][j] : 0.0f) - lgC) * sgl[i-1][j];
                float w0 = __expf(lgC);                 // exp(log(guard(t))) = guard(t)
                float rr = (float)rll[i][j];
                float rw = (rr <= 0.0f) ? 1e7f : rr;    // rcp(guard(t))
                float v = w0 - RATE * 2.0f * acc * rw;
                if (lvl == K_ITERS - 1) {
                    if (col < WP) tout[m] = v;          // interior => col >= 0, m valid
                } else {
                    lgn[i][j] = __logf(v <= 0.0f ? EPSV : v);
                    rll[i][j] = (half_t)fast_rcp(v);
                }
            }
        });
        __syncthreads();
    }
}

// ---------------------------------------------------------------------------
// final dehaze from t_100
// ---------------------------------------------------------------------------
__global__ void out_kernel(const float* __restrict__ t, const half_t* __restrict__ img_c,
                           const float* __restrict__ A, float* __restrict__ out) {
    int m = blockIdx.x * blockDim.x + threadIdx.x;
    if (m >= NPIX) return;
    float tv = t[m];
    float A0 = A[0], A1 = A[1], A2 = A[2];
    float r = 1.0f / tv;               // precise div for the final output
    out[3*m+0] = ((float)img_c[3*m+0] - A0) * r + A0;
    out[3*m+1] = ((float)img_c[3*m+1] - A1) * r + A1;
    out[3*m+2] = ((float)img_c[3*m+2] - A2) * r + A2;
}

extern "C" void kernel_launch(void* const* d_in, const int* in_sizes, int n_in,
                              void* d_out, int out_size, void* d_ws, size_t ws_size,
                              hipStream_t stream) {
    const float* img = (const float*)d_in[0];
    const float* A   = (const float*)d_in[1];
    // workspace: t_a[N] f32 | t_b[N] f32 | img_c[3N] f16
    float*  ws    = (float*)d_ws;
    float*  t_a   = ws;
    float*  t_b   = t_a + NPIX;
    half_t* img_c = (half_t*)(t_b + NPIX);

    dim3 blk2(256, 1, 1);
    dim3 grd2((WP + 255) / 256, HP, 1);
    int blk1 = 256;
    int grd1 = (NPIX + blk1 - 1) / blk1;

    hipLaunchKernelGGL(init_kernel, grd2, blk2, 0, stream, img, A, img_c, t_a);

    float* tsrc = t_a;
    float* tdst = t_b;
    for (int d = 0; d < 25; ++d) {               // 25 dispatches x 4 iters = 100
        hipLaunchKernelGGL(tb_kernel, dim3(NBX, NBY), dim3(TBT), 0, stream,
                           tsrc, tdst, img_c, A);
        float* tmp = tsrc; tsrc = tdst; tdst = tmp;
    }
    hipLaunchKernelGGL(out_kernel, dim3(grd1), dim3(blk1), 0, stream,
                       tsrc, img_c, A, (float*)d_out);
}